// Round 3
// baseline (394.712 us; speedup 1.0000x reference)
//
#include <hip/hip_runtime.h>
#include <hip/hip_bf16.h>

using u16    = unsigned short;
using short8 = __attribute__((ext_vector_type(8))) short;
using u16x4  = __attribute__((ext_vector_type(4))) u16;
using f32x4  = __attribute__((ext_vector_type(4))) float;

#define M_DIM 8192   // B*S = 16*512
#define N_DIM 1024   // D_OUT
#define K_DIM 4096   // D_IN

typedef __attribute__((address_space(1))) void gvoid;
typedef __attribute__((address_space(3))) void svoid;
#define GLOAD_LDS16(g, s) \
  __builtin_amdgcn_global_load_lds((gvoid*)(void*)(g), (svoid*)(s), 16, 0, 0)

// ---- kernel 1: per-row alpha = mean|W|, Wsgn = sign(W) as bf16 (+1/-1/0 exact)
__global__ __launch_bounds__(256) void wprep_kernel(const float* __restrict__ W,
                                                    u16* __restrict__ Wsgn,
                                                    float* __restrict__ alpha) {
  const int row = blockIdx.x;
  const int t   = threadIdx.x;
  const float4* wr = (const float4*)(W + (size_t)row * K_DIM);
  float4 v[4];
  float s = 0.f;
#pragma unroll
  for (int j = 0; j < 4; ++j) {
    v[j] = wr[t + 256 * j];
    s += fabsf(v[j].x) + fabsf(v[j].y) + fabsf(v[j].z) + fabsf(v[j].w);
  }
#pragma unroll
  for (int off = 32; off > 0; off >>= 1) s += __shfl_down(s, off, 64);
  __shared__ float red[4];
  if ((t & 63) == 0) red[t >> 6] = s;
  __syncthreads();
  if (t == 0) alpha[row] = (red[0] + red[1] + red[2] + red[3]) * (1.0f / K_DIM);
  u16x4* dst = (u16x4*)(Wsgn + (size_t)row * K_DIM);
#pragma unroll
  for (int j = 0; j < 4; ++j) {
    u16x4 sg;
    sg[0] = v[j].x > 0.f ? 0x3F80 : (v[j].x < 0.f ? 0xBF80 : 0);
    sg[1] = v[j].y > 0.f ? 0x3F80 : (v[j].y < 0.f ? 0xBF80 : 0);
    sg[2] = v[j].z > 0.f ? 0x3F80 : (v[j].z < 0.f ? 0xBF80 : 0);
    sg[3] = v[j].w > 0.f ? 0x3F80 : (v[j].w < 0.f ? 0xBF80 : 0);
    dst[t + 256 * j] = sg;
  }
}

// fp32x8 -> bf16x8 (RNE) via v_cvt_pk_bf16_f32.
__device__ __forceinline__ short8 pack_bf16x8(f32x4 lo, f32x4 hi) {
  union { short8 s; __hip_bfloat162 h[4]; } u;
  u.h[0] = __float22bfloat162_rn(make_float2(lo[0], lo[1]));
  u.h[1] = __float22bfloat162_rn(make_float2(lo[2], lo[3]));
  u.h[2] = __float22bfloat162_rn(make_float2(hi[0], hi[1]));
  u.h[3] = __float22bfloat162_rn(make_float2(hi[2], hi[3]));
  return u.s;
}

// ---- kernel 2: GEMM C[m,n] = sum_k A[m,k]*Wsgn[n,k], epilogue *alpha + b + resid
// Round 7: double-buffered 2-phase pipeline (catalog T3-minimum) + reg-staged
// fp32 A (T14 issue-early / write-late). Rounds 1-2 showed the old structure is
// serial-latency-bound (every pipe <18% busy): issue loads -> vmcnt(0) -> barrier
// -> compute, nothing overlapped. Now per K-iter:
//   { issue A(t+1)->regs, B(t+1)->LDS[c^1] | MFMA on LDS[c] | vmcnt(0),
//     cvt A->bf16, ds_write LDS[c^1] | barrier }
// so global-load latency hides under the MFMA block. LDS stays bf16
// (2 x 32 KB dbuf = 64 KB -> 2 blocks/CU); no cast kernel, no 64 MiB Abf.
// Fragment addressing identical to the zero-conflict round-0 layout:
// lA/lB [128 rows][8 slots x 16 B], slot s holds k-granule s ^ (row&7).
__global__ __launch_bounds__(256) void gemm_kernel(const float* __restrict__ A,
                                                   const u16* __restrict__ Bsgn,
                                                   const float* __restrict__ alpha,
                                                   const float* __restrict__ bias,
                                                   const float* __restrict__ resid,
                                                   float* __restrict__ out) {
  __shared__ u16 lA[2][128 * 64];   // 2 x 16 KB bf16
  __shared__ u16 lB[2][128 * 64];   // 2 x 16 KB bf16
  const int tid  = threadIdx.x;
  const int wave = tid >> 6;
  const int lane = tid & 63;
  const int quad = lane >> 4;
  const int l16  = lane & 15;
  const int wm   = (wave >> 1) * 64;
  const int wn   = (wave & 1) * 64;

  // XCD swizzle: 512 blocks; xcd = b&7 owns M-bands, all 8 N-tiles per band.
  const int b    = blockIdx.x;
  const int xcd  = b & 7;
  const int l    = b >> 3;                        // 0..63
  const size_t m0 = (size_t)(xcd * 8 + (l >> 3)) * 128;
  const size_t n0 = (size_t)(l & 7) * 128;

  f32x4 acc[4][4] = {};

  // B staging: pure DMA, 16 chunks x 1 KB (8 rows x 8 slots x 16 B), 4/wave.
  const int r8 = lane >> 3;
  const int s_ = lane & 7;
  const u16* bsrc[4];
  int        bdstoff[4];
#pragma unroll
  for (int j = 0; j < 4; ++j) {
    const int c = wave * 4 + j;                   // chunk 0..15
    bsrc[j]    = Bsgn + (n0 + (size_t)(c * 8 + r8)) * K_DIM + (size_t)((s_ ^ r8) * 8);
    bdstoff[j] = c * 512;                         // u16 offset: 1 KB per chunk
  }

  // A staging: global fp32 -> regs -> cvt -> ds_write (swizzled bf16 layout).
  // thread -> (row = tid>>1, half h = tid&1): 32 floats = k [h*32, h*32+32).
  const int arow = tid >> 1;
  const int ah   = tid & 1;
  const float* asrc = A + (m0 + (size_t)arow) * K_DIM + ah * 32;
  int awoff[4];
#pragma unroll
  for (int g = 0; g < 4; ++g) {
    const int G = ah * 4 + g;                     // granule 0..7 (k = G*8..G*8+8)
    awoff[g] = arow * 64 + ((G ^ (arow & 7)) * 8);
  }

  f32x4 ar[8];

#define A_ISSUE(K0)                                                        \
  _Pragma("unroll")                                                        \
  for (int j = 0; j < 8; ++j) ar[j] = *(const f32x4*)(asrc + (K0) + j * 4);

#define B_ISSUE(K0, BUF)                                                   \
  _Pragma("unroll")                                                        \
  for (int j = 0; j < 4; ++j) GLOAD_LDS16(bsrc[j] + (K0), &lB[BUF][bdstoff[j]]);

#define A_WRITE(BUF)                                                       \
  _Pragma("unroll")                                                        \
  for (int g = 0; g < 4; ++g)                                              \
    *(short8*)(&lA[BUF][awoff[g]]) = pack_bf16x8(ar[2 * g], ar[2 * g + 1]);

#define COMPUTE(BUF)                                                       \
  _Pragma("unroll")                                                        \
  for (int s = 0; s < 2; ++s) {                                            \
    const int kq = s * 4 + quad;                                           \
    short8 af[4], bf[4];                                                   \
    _Pragma("unroll")                                                      \
    for (int mt = 0; mt < 4; ++mt) {                                       \
      const int row = wm + mt * 16 + l16;                                  \
      af[mt] = *(const short8*)(&lA[BUF][row * 64 + ((kq ^ (row & 7)) * 8)]); \
    }                                                                      \
    _Pragma("unroll")                                                      \
    for (int nt = 0; nt < 4; ++nt) {                                       \
      const int col = wn + nt * 16 + l16;                                  \
      bf[nt] = *(const short8*)(&lB[BUF][col * 64 + ((kq ^ (col & 7)) * 8)]); \
    }                                                                      \
    _Pragma("unroll")                                                      \
    for (int mt = 0; mt < 4; ++mt)                                         \
      _Pragma("unroll")                                                    \
      for (int nt = 0; nt < 4; ++nt)                                       \
        acc[mt][nt] = __builtin_amdgcn_mfma_f32_16x16x32_bf16(af[mt], bf[nt], \
                                                              acc[mt][nt], 0, 0, 0); \
  }

  // prologue: stage tile 0 into buffer 0
  A_ISSUE(0);
  B_ISSUE(0, 0);
  A_WRITE(0);            // compiler inserts vmcnt wait for ar deps
  __syncthreads();       // drains vmcnt (B DMA) + lgkmcnt (A writes)

  int cur = 0;
#pragma unroll 1
  for (int k0 = 0; k0 < K_DIM - 64; k0 += 64) {
    A_ISSUE(k0 + 64);
    B_ISSUE(k0 + 64, cur ^ 1);
    COMPUTE(cur);
    asm volatile("s_waitcnt vmcnt(0)" ::: "memory");  // pin drain after MFMA
    A_WRITE(cur ^ 1);
    __syncthreads();
    cur ^= 1;
  }
  COMPUTE(cur);          // last tile, no prefetch

  // epilogue: x = acc*alpha[n] + b[n] + resid ; C/D map: col=l16, row=quad*4+r
#pragma unroll
  for (int nt = 0; nt < 4; ++nt) {
    const size_t n  = n0 + wn + nt * 16 + l16;
    const float  al = alpha[n];
    const float  bi = bias[n];
#pragma unroll
    for (int mt = 0; mt < 4; ++mt) {
      const size_t mbase = m0 + wm + mt * 16 + quad * 4;
#pragma unroll
      for (int r = 0; r < 4; ++r) {
        const size_t mm = mbase + r;
        out[mm * N_DIM + n] = acc[mt][nt][r] * al + bi + resid[mm * N_DIM + n];
      }
    }
  }
#undef A_ISSUE
#undef B_ISSUE
#undef A_WRITE
#undef COMPUTE
}

// ---- kernel 3: LayerNorm over last dim (1024), in-place on d_out
__global__ __launch_bounds__(256) void ln_kernel(float* __restrict__ x,
                                                 const float* __restrict__ gamma,
                                                 const float* __restrict__ beta) {
  const size_t row = blockIdx.x;
  float4* xr = (float4*)(x + row * N_DIM);
  const int t = threadIdx.x;
  float4 v = xr[t];
  float s  = v.x + v.y + v.z + v.w;
  float sq = v.x * v.x + v.y * v.y + v.z * v.z + v.w * v.w;
#pragma unroll
  for (int off = 32; off > 0; off >>= 1) {
    s  += __shfl_down(s, off, 64);
    sq += __shfl_down(sq, off, 64);
  }
  __shared__ float rs[4], rq[4];
  if ((t & 63) == 0) { rs[t >> 6] = s; rq[t >> 6] = sq; }
  __syncthreads();
  s  = rs[0] + rs[1] + rs[2] + rs[3];
  sq = rq[0] + rq[1] + rq[2] + rq[3];
  const float mu  = s * (1.0f / N_DIM);
  float var = sq * (1.0f / N_DIM) - mu * mu;
  var = fmaxf(var, 0.0f);
  const float inv = rsqrtf(var + 1e-12f);
  const float4 g = ((const float4*)gamma)[t];
  const float4 b = ((const float4*)beta)[t];
  v.x = g.x * ((v.x - mu) * inv) + b.x;
  v.y = g.y * ((v.y - mu) * inv) + b.y;
  v.z = g.z * ((v.z - mu) * inv) + b.z;
  v.w = g.w * ((v.w - mu) * inv) + b.w;
  xr[t] = v;
}

extern "C" void kernel_launch(void* const* d_in, const int* in_sizes, int n_in,
                              void* d_out, int out_size, void* d_ws, size_t ws_size,
                              hipStream_t stream) {
  const float* hidden = (const float*)d_in[0];  // [16,512,4096]
  const float* resid  = (const float*)d_in[1];  // [16,512,1024]
  const float* W      = (const float*)d_in[2];  // [1024,4096]
  const float* bias   = (const float*)d_in[3];  // [1024]
  const float* gamma  = (const float*)d_in[4];  // [1024]
  const float* beta   = (const float*)d_in[5];  // [1024]
  float* out = (float*)d_out;                   // [16,512,1024] fp32

  char* ws = (char*)d_ws;
  u16*   Wsgn  = (u16*)ws;                                   // 8 MiB
  float* alpha = (float*)(ws + 8ull * 1024 * 1024);          // 4 KiB

  wprep_kernel<<<N_DIM, 256, 0, stream>>>(W, Wsgn, alpha);

  const int nblocks = (N_DIM / 128) * (M_DIM / 128);  // 512, 1D swizzled grid
  gemm_kernel<<<nblocks, 256, 0, stream>>>(hidden, Wsgn, alpha, bias, resid, out);

  ln_kernel<<<M_DIM, 256, 0, stream>>>(out, gamma, beta);
}

// Round 4
// 350.327 us; speedup vs baseline: 1.1267x; 1.1267x over previous
//
#include <hip/hip_runtime.h>

using u16    = unsigned short;
using short8 = __attribute__((ext_vector_type(8))) short;
using u16x8  = __attribute__((ext_vector_type(8))) u16;
using u16x4  = __attribute__((ext_vector_type(4))) u16;
using f32x4  = __attribute__((ext_vector_type(4))) float;

#define M_DIM 8192   // B*S = 16*512
#define N_DIM 1024   // D_OUT
#define K_DIM 4096   // D_IN

typedef __attribute__((address_space(1))) void gvoid;
typedef __attribute__((address_space(3))) void svoid;
#define GLOAD_LDS16(g, s) \
  __builtin_amdgcn_global_load_lds((gvoid*)(void*)(g), (svoid*)(s), 16, 0, 0)

__device__ __forceinline__ u16 f2bf(float f) {
  unsigned u = __builtin_bit_cast(unsigned, f);
  u = (u + 0x7FFFu + ((u >> 16) & 1u)) >> 16;   // RNE
  return (u16)u;
}

// ---- kernel 1: per-row alpha = mean|W|, Wsgn = sign(W) as bf16 (+1/-1/0 exact)
__global__ __launch_bounds__(256) void wprep_kernel(const float* __restrict__ W,
                                                    u16* __restrict__ Wsgn,
                                                    float* __restrict__ alpha) {
  const int row = blockIdx.x;
  const int t   = threadIdx.x;
  const float4* wr = (const float4*)(W + (size_t)row * K_DIM);
  float4 v[4];
  float s = 0.f;
#pragma unroll
  for (int j = 0; j < 4; ++j) {
    v[j] = wr[t + 256 * j];
    s += fabsf(v[j].x) + fabsf(v[j].y) + fabsf(v[j].z) + fabsf(v[j].w);
  }
#pragma unroll
  for (int off = 32; off > 0; off >>= 1) s += __shfl_down(s, off, 64);
  __shared__ float red[4];
  if ((t & 63) == 0) red[t >> 6] = s;
  __syncthreads();
  if (t == 0) alpha[row] = (red[0] + red[1] + red[2] + red[3]) * (1.0f / K_DIM);
  u16x4* dst = (u16x4*)(Wsgn + (size_t)row * K_DIM);
#pragma unroll
  for (int j = 0; j < 4; ++j) {
    u16x4 sg;
    sg[0] = v[j].x > 0.f ? 0x3F80 : (v[j].x < 0.f ? 0xBF80 : 0);
    sg[1] = v[j].y > 0.f ? 0x3F80 : (v[j].y < 0.f ? 0xBF80 : 0);
    sg[2] = v[j].z > 0.f ? 0x3F80 : (v[j].z < 0.f ? 0xBF80 : 0);
    sg[3] = v[j].w > 0.f ? 0x3F80 : (v[j].w < 0.f ? 0xBF80 : 0);
    dst[t + 256 * j] = sg;
  }
}

// ---- kernel 2: hidden fp32 -> bf16 (8 elems/thread)
__global__ __launch_bounds__(256) void cast_kernel(const float* __restrict__ in,
                                                   u16* __restrict__ out) {
  const size_t i = ((size_t)blockIdx.x * 256 + threadIdx.x) * 8;
  float4 a = ((const float4*)(in + i))[0];
  float4 b = ((const float4*)(in + i))[1];
  u16x8 p;
  p[0] = f2bf(a.x); p[1] = f2bf(a.y); p[2] = f2bf(a.z); p[3] = f2bf(a.w);
  p[4] = f2bf(b.x); p[5] = f2bf(b.y); p[6] = f2bf(b.z); p[7] = f2bf(b.w);
  *(u16x8*)(out + i) = p;
}

// ---- kernel 3: GEMM C[m,n] = sum_k A[m,k]*Wsgn[n,k], epilogue *alpha + b + resid
// Round 8: round-0 structure (pure-DMA bf16 staging, zero-conflict XOR layout,
// XCD swizzle) + the validated T3-minimum 2-phase pipeline:
//   prologue: STAGE(buf0); sync;
//   loop:     STAGE(buf^1, t+1); COMPUTE(buf); sync; flip;   // ONE barrier/iter
// The tile-t+1 DMA latency hides under COMPUTE(t); the barrier's implicit
// vmcnt(0)+lgkmcnt(0) drain happens after compute, not before it (round-0
// exposed the full load latency every iter: STAGE -> drain -> barrier -> MFMA).
// `cur` is runtime (unroll 1) so the compiler cannot alias-prove the prefetch
// against COMPUTE's ds_reads and sink it.
// LDS: lA/lB [2 bufs][128 rows][8 slots x 16 B], slot s holds k-granule
// s ^ (row&7); swizzle folded into per-lane DMA SOURCE address.
template <bool PRE>
__global__ __launch_bounds__(256) void gemm_kernel(const void* __restrict__ Aopaque,
                                                   const u16* __restrict__ Bsgn,
                                                   const float* __restrict__ alpha,
                                                   const float* __restrict__ bias,
                                                   const float* __restrict__ resid,
                                                   float* __restrict__ out) {
  __shared__ u16 lA[2][128 * 64];   // 2 x 16 KB
  __shared__ u16 lB[2][128 * 64];   // 2 x 16 KB
  const int tid  = threadIdx.x;
  const int wave = tid >> 6;
  const int lane = tid & 63;
  const int quad = lane >> 4;
  const int l16  = lane & 15;
  const int wm   = (wave >> 1) * 64;
  const int wn   = (wave & 1) * 64;

  // XCD swizzle: 512 blocks; xcd = b&7 owns M-bands, all 8 N-tiles per band.
  const int b    = blockIdx.x;
  const int xcd  = b & 7;
  const int l    = b >> 3;                        // 0..63
  const size_t m0 = (size_t)(xcd * 8 + (l >> 3)) * 128;
  const size_t n0 = (size_t)(l & 7) * 128;

  f32x4 acc[4][4] = {};

  // DMA staging: 16 chunks x 1 KB per matrix (8 rows x 8 slots x 16 B), 4/wave.
  // lane -> (row8 = lane>>3, slot = lane&7); source granule = slot ^ row8.
  const int r8  = lane >> 3;
  const int kgs = ((lane & 7) ^ r8) * 8;          // source k elem offset
  const u16* bsrc[4];
  const u16* asrc16[4];
  int        coff[4];
#pragma unroll
  for (int j = 0; j < 4; ++j) {
    const int c = wave * 4 + j;                   // chunk 0..15
    bsrc[j] = Bsgn + (n0 + (size_t)c * 8 + r8) * K_DIM + kgs;
    if constexpr (PRE)
      asrc16[j] = (const u16*)Aopaque + (m0 + (size_t)c * 8 + r8) * K_DIM + kgs;
    coff[j] = c * 512;                            // u16 offset of 1 KB chunk
  }

#define STAGE(K0, BUF)                                                         \
  do {                                                                         \
    _Pragma("unroll")                                                          \
    for (int j = 0; j < 4; ++j) GLOAD_LDS16(bsrc[j] + (K0), &lB[BUF][coff[j]]); \
    if constexpr (PRE) {                                                       \
      _Pragma("unroll")                                                        \
      for (int j = 0; j < 4; ++j) GLOAD_LDS16(asrc16[j] + (K0), &lA[BUF][coff[j]]); \
    } else {                                                                   \
      const float* Af = (const float*)Aopaque;                                 \
      const int row = tid >> 1;                                                \
      const int h   = tid & 1;                                                 \
      _Pragma("unroll")                                                        \
      for (int g = 0; g < 4; ++g) {                                            \
        const int kg = h * 4 + g;                                              \
        const float4* src = (const float4*)(Af + (m0 + row) * (size_t)K_DIM +  \
                                            (K0) + kg * 8);                    \
        float4 f0 = src[0], f1 = src[1];                                       \
        u16x8 p;                                                               \
        p[0] = f2bf(f0.x); p[1] = f2bf(f0.y); p[2] = f2bf(f0.z); p[3] = f2bf(f0.w); \
        p[4] = f2bf(f1.x); p[5] = f2bf(f1.y); p[6] = f2bf(f1.z); p[7] = f2bf(f1.w); \
        *(u16x8*)(&lA[BUF][row * 64 + ((kg ^ (row & 7)) * 8)]) = p;            \
      }                                                                        \
    }                                                                          \
  } while (0)

#define COMPUTE(BUF)                                                           \
  do {                                                                         \
    _Pragma("unroll")                                                          \
    for (int s = 0; s < 2; ++s) {                                              \
      const int kq = s * 4 + quad;                                             \
      short8 af[4], bf[4];                                                     \
      _Pragma("unroll")                                                        \
      for (int mt = 0; mt < 4; ++mt) {                                         \
        const int row = wm + mt * 16 + l16;                                    \
        af[mt] = *(const short8*)(&lA[BUF][row * 64 + ((kq ^ (row & 7)) * 8)]); \
      }                                                                        \
      _Pragma("unroll")                                                        \
      for (int nt = 0; nt < 4; ++nt) {                                         \
        const int col = wn + nt * 16 + l16;                                    \
        bf[nt] = *(const short8*)(&lB[BUF][col * 64 + ((kq ^ (col & 7)) * 8)]); \
      }                                                                        \
      _Pragma("unroll")                                                        \
      for (int mt = 0; mt < 4; ++mt)                                           \
        _Pragma("unroll")                                                      \
        for (int nt = 0; nt < 4; ++nt)                                         \
          acc[mt][nt] = __builtin_amdgcn_mfma_f32_16x16x32_bf16(af[mt], bf[nt], \
                                                                acc[mt][nt], 0, 0, 0); \
    }                                                                          \
  } while (0)

  // prologue: stage tile 0 into buffer 0 (sync drains vmcnt+lgkmcnt)
  STAGE(0, 0);
  __syncthreads();

  int cur = 0;
#pragma unroll 1
  for (int k0 = 0; k0 < K_DIM - 64; k0 += 64) {
    STAGE(k0 + 64, cur ^ 1);   // issue prefetch BEFORE compute
    COMPUTE(cur);              // DMA latency hides under MFMA + ds_read
    __syncthreads();           // one drain+barrier per iter, after compute
    cur ^= 1;
  }
  COMPUTE(cur);                // last tile, no prefetch

  // epilogue: x = acc*alpha[n] + b[n] + resid ; C/D map: col=l16, row=quad*4+r
#pragma unroll
  for (int nt = 0; nt < 4; ++nt) {
    const size_t n  = n0 + wn + nt * 16 + l16;
    const float  al = alpha[n];
    const float  bi = bias[n];
#pragma unroll
    for (int mt = 0; mt < 4; ++mt) {
      const size_t mbase = m0 + wm + mt * 16 + quad * 4;
#pragma unroll
      for (int r = 0; r < 4; ++r) {
        const size_t mm = mbase + r;
        out[mm * N_DIM + n] = acc[mt][nt][r] * al + bi + resid[mm * N_DIM + n];
      }
    }
  }
#undef STAGE
#undef COMPUTE
}

// ---- kernel 4: LayerNorm over last dim (1024), in-place on d_out
__global__ __launch_bounds__(256) void ln_kernel(float* __restrict__ x,
                                                 const float* __restrict__ gamma,
                                                 const float* __restrict__ beta) {
  const size_t row = blockIdx.x;
  float4* xr = (float4*)(x + row * N_DIM);
  const int t = threadIdx.x;
  float4 v = xr[t];
  float s  = v.x + v.y + v.z + v.w;
  float sq = v.x * v.x + v.y * v.y + v.z * v.z + v.w * v.w;
#pragma unroll
  for (int off = 32; off > 0; off >>= 1) {
    s  += __shfl_down(s, off, 64);
    sq += __shfl_down(sq, off, 64);
  }
  __shared__ float rs[4], rq[4];
  if ((t & 63) == 0) { rs[t >> 6] = s; rq[t >> 6] = sq; }
  __syncthreads();
  s  = rs[0] + rs[1] + rs[2] + rs[3];
  sq = rq[0] + rq[1] + rq[2] + rq[3];
  const float mu  = s * (1.0f / N_DIM);
  float var = sq * (1.0f / N_DIM) - mu * mu;
  var = fmaxf(var, 0.0f);
  const float inv = rsqrtf(var + 1e-12f);
  const float4 g = ((const float4*)gamma)[t];
  const float4 b = ((const float4*)beta)[t];
  v.x = g.x * ((v.x - mu) * inv) + b.x;
  v.y = g.y * ((v.y - mu) * inv) + b.y;
  v.z = g.z * ((v.z - mu) * inv) + b.z;
  v.w = g.w * ((v.w - mu) * inv) + b.w;
  xr[t] = v;
}

extern "C" void kernel_launch(void* const* d_in, const int* in_sizes, int n_in,
                              void* d_out, int out_size, void* d_ws, size_t ws_size,
                              hipStream_t stream) {
  const float* hidden = (const float*)d_in[0];  // [16,512,4096]
  const float* resid  = (const float*)d_in[1];  // [16,512,1024]
  const float* W      = (const float*)d_in[2];  // [1024,4096]
  const float* bias   = (const float*)d_in[3];  // [1024]
  const float* gamma  = (const float*)d_in[4];  // [1024]
  const float* beta   = (const float*)d_in[5];  // [1024]
  float* out = (float*)d_out;                   // [16,512,1024] fp32

  char* ws = (char*)d_ws;
  u16*   Wsgn  = (u16*)ws;                                   // 8 MiB
  float* alpha = (float*)(ws + 8ull * 1024 * 1024);          // 4 KiB
  u16*   Abf   = (u16*)(ws + 8ull * 1024 * 1024 + 4096);     // 64 MiB (path A)
  const size_t need_full = 8ull * 1024 * 1024 + 4096 + 64ull * 1024 * 1024;

  wprep_kernel<<<N_DIM, 256, 0, stream>>>(W, Wsgn, alpha);

  const int nblocks = (N_DIM / 128) * (M_DIM / 128);  // 512, 1D swizzled grid
  if (ws_size >= need_full) {
    cast_kernel<<<(M_DIM * (size_t)K_DIM) / (256 * 8), 256, 0, stream>>>(hidden, Abf);
    gemm_kernel<true><<<nblocks, 256, 0, stream>>>((const void*)Abf, Wsgn, alpha,
                                                   bias, resid, out);
  } else {
    gemm_kernel<false><<<nblocks, 256, 0, stream>>>((const void*)hidden, Wsgn, alpha,
                                                    bias, resid, out);
  }
  ln_kernel<<<M_DIM, 256, 0, stream>>>(out, gamma, beta);
}